// Round 1
// baseline (26.787 us; speedup 1.0000x reference)
//
#include <hip/hip_runtime.h>

// Problem constants (match reference)
#define BB 64
#define HH 480
#define WW 640
#define PP 8192
#define CHUNKS 8           // blocks per batch in kernel 1
#define TPB 256            // threads per block
// pairs per thread = PP / CHUNKS / TPB = 4 (one int4 load per index array)

__global__ __launch_bounds__(TPB) void rdl_partial(
    const float* __restrict__ depth,   // [B, H*W]
    const int*  __restrict__ xA,
    const int*  __restrict__ yA,
    const int*  __restrict__ xB,
    const int*  __restrict__ yB,
    const int*  __restrict__ rel,
    float4*     __restrict__ ws)       // [B*CHUNKS] partials
{
    const int blk = blockIdx.x;
    const int b   = blk >> 3;          // / CHUNKS
    const int c   = blk & (CHUNKS - 1);
    const int tid = threadIdx.x;
    const int pair0 = b * PP + c * (PP / CHUNKS) + tid * 4;

    const int4 xa4 = *reinterpret_cast<const int4*>(xA  + pair0);
    const int4 ya4 = *reinterpret_cast<const int4*>(yA  + pair0);
    const int4 xb4 = *reinterpret_cast<const int4*>(xB  + pair0);
    const int4 yb4 = *reinterpret_cast<const int4*>(yB  + pair0);
    const int4 rr4 = *reinterpret_cast<const int4*>(rel + pair0);

    const int xas[4] = {xa4.x, xa4.y, xa4.z, xa4.w};
    const int yas[4] = {ya4.x, ya4.y, ya4.z, ya4.w};
    const int xbs[4] = {xb4.x, xb4.y, xb4.z, xb4.w};
    const int ybs[4] = {yb4.x, yb4.y, yb4.z, yb4.w};
    const int rs [4] = {rr4.x, rr4.y, rr4.z, rr4.w};

    const float* __restrict__ d = depth + (size_t)b * (HH * WW);

    float s_log = 0.f, s_sq = 0.f;
    int   n_log = 0,   n_sq = 0;

    // Issue all 8 gathers up front for ILP (independent loads).
    float zA[4], zB[4];
#pragma unroll
    for (int k = 0; k < 4; ++k) {
        zA[k] = d[xas[k] * WW + yas[k]];
        zB[k] = d[xbs[k] * WW + ybs[k]];
    }

#pragma unroll
    for (int k = 0; k < 4; ++k) {
        const float pred = zA[k] - zB[k];
        const int r = rs[k];
        if (r != 2) {
            if (r == 0) {
                s_sq += pred * pred;
                n_sq++;
            } else {
                const float x = -(float)r * pred;
                // stable softplus: max(x,0) + log1p(exp(-|x|))
                s_log += fmaxf(x, 0.f) + log1pf(expf(-fabsf(x)));
                n_log++;
            }
        }
    }

    // wave (64-lane) reduction
#pragma unroll
    for (int off = 32; off > 0; off >>= 1) {
        s_log += __shfl_down(s_log, off);
        s_sq  += __shfl_down(s_sq,  off);
        n_log += __shfl_down(n_log, off);
        n_sq  += __shfl_down(n_sq,  off);
    }

    __shared__ float4 lds[TPB / 64];
    const int wave = tid >> 6;
    if ((tid & 63) == 0)
        lds[wave] = make_float4(s_log, s_sq, (float)n_log, (float)n_sq);
    __syncthreads();

    if (tid == 0) {
        float4 acc = lds[0];
#pragma unroll
        for (int wv = 1; wv < TPB / 64; ++wv) {
            acc.x += lds[wv].x;
            acc.y += lds[wv].y;
            acc.z += lds[wv].z;
            acc.w += lds[wv].w;
        }
        ws[blk] = acc;
    }
}

__global__ __launch_bounds__(64) void rdl_final(
    const float4* __restrict__ ws,     // [B*CHUNKS]
    float*        __restrict__ out)
{
    const int b = threadIdx.x;         // 64 threads, one per batch
    float sl = 0.f, ss = 0.f, nl = 0.f, ns = 0.f;
#pragma unroll
    for (int c = 0; c < CHUNKS; ++c) {
        const float4 v = ws[b * CHUNKS + c];
        sl += v.x; ss += v.y; nl += v.z; ns += v.w;
    }
    float loss = sl / nl + ss / ns;    // per-batch log_loss + sq_loss
#pragma unroll
    for (int off = 32; off > 0; off >>= 1)
        loss += __shfl_down(loss, off);
    if (b == 0)
        out[0] = loss * (1.0f / (float)BB);
}

extern "C" void kernel_launch(void* const* d_in, const int* in_sizes, int n_in,
                              void* d_out, int out_size, void* d_ws, size_t ws_size,
                              hipStream_t stream) {
    const float* depth = (const float*)d_in[0];
    const int*   xA    = (const int*)d_in[1];
    const int*   yA    = (const int*)d_in[2];
    const int*   xB    = (const int*)d_in[3];
    const int*   yB    = (const int*)d_in[4];
    const int*   rel   = (const int*)d_in[5];
    float*       out   = (float*)d_out;
    float4*      ws    = (float4*)d_ws;   // needs BB*CHUNKS*16 = 8 KiB

    rdl_partial<<<BB * CHUNKS, TPB, 0, stream>>>(depth, xA, yA, xB, yB, rel, ws);
    rdl_final<<<1, 64, 0, stream>>>(ws, out);
}